// Round 20
// baseline (272.191 us; speedup 1.0000x reference)
//
#include <hip/hip_runtime.h>
#include <hip/hip_fp16.h>

typedef _Float16 f16;
typedef _Float16 f16x8 __attribute__((ext_vector_type(8)));
typedef _Float16 f16x4 __attribute__((ext_vector_type(4)));
typedef float f32x4 __attribute__((ext_vector_type(4)));

#define GLB(p) ((const __attribute__((address_space(1))) void*)(p))
#define LDSP(p) ((__attribute__((address_space(3))) void*)(p))

__device__ __forceinline__ void gload16(const void* g, void* l) {
  __builtin_amdgcn_global_load_lds(GLB(g), LDSP(l), 16, 0, 0);
}

#define VMW(n) asm volatile("s_waitcnt vmcnt(" #n ")" ::: "memory")
__device__ __forceinline__ void barrier_fenced() {
  asm volatile("" ::: "memory");
  __builtin_amdgcn_s_barrier();
  asm volatile("" ::: "memory");
}

// ---------------- prep_all3: xpose + weight permute + bo2 partials ----------------
// blocks 0..511    : xpose  (x -> xb [t][c] f16, xbT [bc][c][t] f16)
// blocks 512..2559 : weights (WqT2/WkT2/WvT2[h*256+c][d] = W[c][d*8+h];
//                             WoT[dm][h*256+d] = Wo[(d*8+h)][dm])
// blocks 2560..2563: bo2p[p][dm] = sum_{r in p-range} Wo[r][dm]*bv[r]
//                    (coalesced across dm; summed with bo in reduce2b)
__global__ __launch_bounds__(256) void prep_all3(
    const float* __restrict__ x, const float* __restrict__ Wq,
    const float* __restrict__ Wk, const float* __restrict__ Wv,
    const float* __restrict__ Wo, const float* __restrict__ bv,
    f16* __restrict__ xb, f16* __restrict__ xbT, f16* __restrict__ WqT2,
    f16* __restrict__ WkT2, f16* __restrict__ WvT2, f16* __restrict__ WoT,
    float* __restrict__ bo2p) {
  __shared__ f16 t[32 * 268];
  const int bid = blockIdx.x;
  const int tid = threadIdx.x;
  if (bid < 512) {
    // ---- xpose ----
    const int bc = bid >> 3, tt = bid & 7;
    const long tbase = (long)(bc * 256 + tt * 32);
#pragma unroll
    for (int i = 0; i < 8; ++i) {
      int tr = (tid >> 6) + i * 4;  // 0..31
      int c4 = (tid & 63) * 4;
      float4 v = *(const float4*)(x + (tbase + tr) * 256 + c4);
      f16x4 o = {(f16)v.x, (f16)v.y, (f16)v.z, (f16)v.w};
      *(f16x4*)(xb + (tbase + tr) * 256 + c4) = o;
      *(f16x4*)(&t[tr * 268 + c4]) = o;
    }
    __syncthreads();
#pragma unroll
    for (int i = 0; i < 8; ++i) {
      int c = (tid >> 3) + i * 32;  // 0..255
      int t0 = (tid & 7) * 4;       // 0..28
      f16x4 v;
#pragma unroll
      for (int j = 0; j < 4; ++j) v[j] = t[(t0 + j) * 268 + c];
      *(f16x4*)(&xbT[(long)bc * 65536 + (long)c * 256 + tt * 32 + t0]) = v;
    }
  } else if (bid < 2560) {
    // ---- weight permute ----
    int g = (bid - 512) * 256 + tid;  // 0..524287
    int hc = g >> 8, d = g & 255;
    int h = hc >> 8, c = hc & 255;
    int src = c * 2048 + d * 8 + h;
    WqT2[g] = (f16)Wq[src];
    WkT2[g] = (f16)Wk[src];
    WvT2[g] = (f16)Wv[src];
    int dm = g >> 11, np = g & 2047;
    WoT[g] = (f16)Wo[((np & 255) * 8 + (np >> 8)) * 256 + dm];
  } else {
    // ---- bo2 partial p: sum over r in [p*512, p*512+512) of Wo[r][dm]*bv[r]
    const int p = bid - 2560;  // 0..3
    const int dm = tid;
    float acc = 0.f;
    for (int r = p * 512; r < p * 512 + 512; ++r)
      acc += Wo[(long)r * 256 + dm] * bv[r];
    bo2p[p * 256 + dm] = acc;
  }
}

// ---------------- gemm_pre2: MT_h, GT_h (MFMA, blocks 0..31) + wv (32..39) ------
// mat0 (MT): MT_h[c'][c] = sum_d Wk_h[c'][d]*Wq_h[c][d]
// mat1 (GT): GT_h[dm][c] = sum_d Wo_h[d][dm]*Wv_h[c][d]
// blocks 32..39: wv[h*256+c] = sum_d WkT2[h*256+c][d]*bq[d*8+h]  (contiguous rows)
__global__ __launch_bounds__(256) void gemm_pre2(
    const f16* __restrict__ WqT2, const f16* __restrict__ WkT2,
    const f16* __restrict__ WvT2, const f16* __restrict__ WoT,
    const float* __restrict__ bq, f16* __restrict__ MT, f16* __restrict__ GT,
    float* __restrict__ wv) {
  const int bid = blockIdx.x;
  const int tid = threadIdx.x;
  if (bid >= 32) {
    // ---- wv for head h (parallel across 8 blocks) ----
    __shared__ float bql[256];
    const int h = bid - 32;
    bql[tid] = bq[tid * 8 + h];  // bql[d] = bq[d*8+h]
    __syncthreads();
    const f16* row = WkT2 + ((h * 256 + tid) << 8);
    float acc = 0.f;
#pragma unroll
    for (int d8 = 0; d8 < 32; ++d8) {
      f16x8 kv = *(const f16x8*)(row + d8 * 8);
#pragma unroll
      for (int e = 0; e < 8; ++e) acc += (float)kv[e] * bql[d8 * 8 + e];
    }
    wv[h * 256 + tid] = acc;
    return;
  }
  __shared__ __align__(16) char smem[49152];  // A 2x8KB @0, B 2x16KB @16384
  const int mat = bid >> 4, h = (bid >> 1) & 7, mt = bid & 1;
  const f16* A;
  long As;
  const f16* B;
  f16* C;
  if (mat == 0) {
    A = WkT2 + h * 65536 + mt * 32768;
    As = 256;
    B = WqT2 + h * 65536;
    C = MT + h * 65536 + mt * 32768;
  } else {
    A = WoT + h * 256 + (long)mt * 128 * 2048;
    As = 2048;
    B = WvT2 + h * 65536;
    C = GT + h * 65536 + mt * 32768;
  }
  const int lane = tid & 63, wid = tid >> 6;  // 4 waves
  const int l15 = lane & 15, lg = lane >> 4;
  const int w32 = wid * 32;

  auto stageA = [&](int ct) {
#pragma unroll
    for (int r = 0; r < 2; ++r) {
      int flat = r * 4096 + tid * 16;
      int row = flat >> 6;
      int kk = ct * 32 + (((flat ^ (((row >> 1) & 3) << 4)) & 63) >> 1);
      gload16(A + (long)row * As + kk, smem + (ct & 1) * 8192 + flat);
    }
  };
  auto stageB = [&](int ct) {
#pragma unroll
    for (int r = 0; r < 4; ++r) {
      int flat = r * 4096 + tid * 16;
      int row = flat >> 6;
      int kk = ct * 32 + (((flat ^ (((row >> 1) & 3) << 4)) & 63) >> 1);
      gload16(B + (long)row * 256 + kk, smem + 16384 + (ct & 1) * 16384 + flat);
    }
  };
  auto ldA = [&](int ct, int row) -> f16x8 {
    return *(const f16x8*)(smem + (ct & 1) * 8192 + row * 64 +
                           ((lg * 16) ^ (((row >> 1) & 3) << 4)));
  };
  auto ldB = [&](int ct, int row) -> f16x8 {
    return *(const f16x8*)(smem + 16384 + (ct & 1) * 16384 + row * 64 +
                           ((lg * 16) ^ (((row >> 1) & 3) << 4)));
  };

  f32x4 acc[2][16] = {};
  stageA(0);
  stageB(0);
  for (int ct = 0; ct < 8; ++ct) {
    VMW(0);
    barrier_fenced();
    if (ct < 7) {
      stageA(ct + 1);
      stageB(ct + 1);
    }
    f16x8 af[2];
#pragma unroll
    for (int i = 0; i < 2; ++i) af[i] = ldA(ct, w32 + i * 16 + l15);
#pragma unroll
    for (int f = 0; f < 16; ++f) {
      f16x8 bf = ldB(ct, f * 16 + l15);
#pragma unroll
      for (int i = 0; i < 2; ++i)
        acc[i][f] = __builtin_amdgcn_mfma_f32_16x16x32_f16(af[i], bf, acc[i][f], 0, 0, 0);
    }
  }
#pragma unroll
  for (int i = 0; i < 2; ++i)
#pragma unroll
    for (int f = 0; f < 16; ++f)
#pragma unroll
      for (int jj = 0; jj < 4; ++jj)
        C[(w32 + i * 16 + lg * 4 + jj) * 256 + f * 16 + l15] = (f16)acc[i][f][jj];
}

// ---------------- vcomp: v[bc][h][j] = sum_c xb[bc][j][c] * wv[h][c] ----------------
__global__ __launch_bounds__(256) void vcomp(const f16* __restrict__ xb,
                                             const float* __restrict__ wv,
                                             float* __restrict__ v) {
  __shared__ float wl[2048];
  const int bc = blockIdx.x, tid = threadIdx.x;
  for (int r = 0; r < 8; ++r) wl[r * 256 + tid] = wv[r * 256 + tid];
  __syncthreads();
  const f16* row = xb + (long)bc * 65536 + (long)tid * 256;
  float a[8] = {};
  for (int c8 = 0; c8 < 32; ++c8) {
    f16x8 xv = *(const f16x8*)(row + c8 * 8);
#pragma unroll
    for (int h = 0; h < 8; ++h) {
      float s = 0.f;
#pragma unroll
      for (int e = 0; e < 8; ++e) s += (float)xv[e] * wl[h * 256 + c8 * 8 + e];
      a[h] += s;
    }
  }
  for (int h = 0; h < 8; ++h) v[bc * 2048 + h * 256 + tid] = a[h];
}

// ---------------- attn_fused6 (round-11/19 verified: 125us, VGPR 100, no spill) ----
__global__ __launch_bounds__(512, 2) void attn_fused6(
    const f16* __restrict__ xb, const f16* __restrict__ xbT,
    const f16* __restrict__ MT, const f16* __restrict__ GT,
    const float* __restrict__ vw, f16* __restrict__ Zp) {
  __shared__ __align__(16) char smem[81920];
  const int tid = threadIdx.x;
  const int lane = tid & 63, wid = tid >> 6;  // 8 waves x 16 rows
  const int l15 = lane & 15, lg = lane >> 4;
  const int w16 = wid * 16;
  const int bc = blockIdx.x, qt = blockIdx.y, h = blockIdx.z;
  const f16* xB = xb + (long)bc * 65536;   // [t][c]
  const f16* xA = xB + qt * 32768;         // this block's 128 q rows
  const f16* xT = xbT + (long)bc * 65536;  // [c][t]
  const f16* MTh = MT + h * 65536;         // [c'][c]
  const f16* GTh = GT + h * 65536;         // [dm][c]

  float vv[2][8];
  {
    const float* vb = vw + bc * 2048 + h * 256;
#pragma unroll
    for (int h2 = 0; h2 < 2; ++h2)
#pragma unroll
      for (int f = 0; f < 8; ++f) vv[h2][f] = vb[h2 * 128 + f * 16 + l15];
  }

  auto stageB8 = [&](const f16* src, int s) {  // [128 rows][32 k] 8KB, 1 pass
    int flat = tid * 16;
    int row = flat >> 6;
    int kk = ((flat ^ (((row >> 1) & 3) << 4)) & 63) >> 1;
    gload16(src + (long)row * 256 + kk, smem + 65536 + (s & 1) * 8192 + flat);
  };
  auto ldB8 = [&](int s, int row) -> f16x8 {
    return *(const f16x8*)(smem + 65536 + (s & 1) * 8192 + row * 64 +
                           ((lg * 16) ^ (((row >> 1) & 3) << 4)));
  };
  auto stageA8 = [&](int ct) {  // xA tile [128][32] into region0 bufs
    int flat = tid * 16;
    int row = flat >> 6;
    int kk = ct * 32 + (((flat ^ (((row >> 1) & 3) << 4)) & 63) >> 1);
    gload16(xA + (long)row * 256 + kk, smem + (ct & 1) * 8192 + flat);
  };
  auto ldA8 = [&](int ct, int row) -> f16x8 {
    return *(const f16x8*)(smem + (ct & 1) * 8192 + row * 64 +
                           ((lg * 16) ^ (((row >> 1) & 3) << 4)));
  };
  auto st0 = [&](int row, int col, f16 val) {
    *(f16*)(smem + row * 512 + ((col * 2) ^ ((row & 7) << 4))) = val;
  };
  auto ld0 = [&](int row, int kt) -> f16x8 {
    return *(const f16x8*)(smem + row * 512 +
                           ((kt * 64 + lg * 16) ^ ((row & 7) << 4)));
  };

  const int arow = w16 + l15;
  f32x4 acc[2][8];

  // ---------- phase T ----------
#pragma unroll
  for (int a = 0; a < 2; ++a)
#pragma unroll
    for (int b = 0; b < 8; ++b) acc[a][b] = (f32x4)(0.f);
  stageA8(0);
  stageB8(MTh, 0);
#pragma unroll
  for (int s = 0; s < 16; ++s) {
    const int ct = s >> 1, h2 = s & 1;
    VMW(0);
    barrier_fenced();
    if (s < 15) {
      const int ns = s + 1;
      stageB8(MTh + (ns & 1) * 32768 + (ns >> 1) * 32, ns);
      if ((ns & 1) == 0) stageA8(ns >> 1);
    }
    f16x8 af = ldA8(ct, arow);
    __builtin_amdgcn_s_setprio(1);
#pragma unroll
    for (int f = 0; f < 8; ++f) {
      f16x8 bf = ldB8(s, f * 16 + l15);
      acc[h2][f] = __builtin_amdgcn_mfma_f32_16x16x32_f16(af, bf, acc[h2][f], 0, 0, 0);
    }
    __builtin_amdgcn_s_setprio(0);
  }
  barrier_fenced();
#pragma unroll
  for (int h2 = 0; h2 < 2; ++h2)
#pragma unroll
    for (int f = 0; f < 8; ++f)
#pragma unroll
      for (int jj = 0; jj < 4; ++jj)
        st0(w16 + lg * 4 + jj, h2 * 128 + f * 16 + l15, (f16)acc[h2][f][jj]);

  // ---------- phase S ----------
#pragma unroll
  for (int a = 0; a < 2; ++a)
#pragma unroll
    for (int b = 0; b < 8; ++b) acc[a][b] = (f32x4)(0.f);
  stageB8(xB, 0);
#pragma unroll
  for (int s = 0; s < 16; ++s) {
    const int ct = s >> 1, jh = s & 1;
    VMW(0);
    barrier_fenced();
    if (s < 15) {
      const int ns = s + 1;
      stageB8(xB + (ns & 1) * 32768 + (ns >> 1) * 32, ns);
    }
    f16x8 af = ld0(arow, ct);
    __builtin_amdgcn_s_setprio(1);
#pragma unroll
    for (int f = 0; f < 8; ++f) {
      f16x8 bf = ldB8(s, f * 16 + l15);
      acc[jh][f] = __builtin_amdgcn_mfma_f32_16x16x32_f16(af, bf, acc[jh][f], 0, 0, 0);
    }
    __builtin_amdgcn_s_setprio(0);
  }
  barrier_fenced();

  // ---------- softmax over 256 j (rows wave-private) ----------
  const float SCL = 0.0625f * 1.44269504089f;
  float inv[4];
#pragma unroll
  for (int jj = 0; jj < 4; ++jj) {
    float m_ = acc[0][0][jj] + vv[0][0];
#pragma unroll
    for (int h2 = 0; h2 < 2; ++h2)
#pragma unroll
      for (int f = 0; f < 8; ++f)
        m_ = fmaxf(m_, acc[h2][f][jj] + vv[h2][f]);
#pragma unroll
    for (int off = 1; off < 16; off <<= 1) m_ = fmaxf(m_, __shfl_xor(m_, off, 64));
    float s_ = 0.f;
#pragma unroll
    for (int h2 = 0; h2 < 2; ++h2)
#pragma unroll
      for (int f = 0; f < 8; ++f) {
        float e = __builtin_exp2f((acc[h2][f][jj] + vv[h2][f] - m_) * SCL);
        acc[h2][f][jj] = e;
        s_ += e;
      }
#pragma unroll
    for (int off = 1; off < 16; off <<= 1) s_ += __shfl_xor(s_, off, 64);
    inv[jj] = 1.f / s_;
  }
#pragma unroll
  for (int h2 = 0; h2 < 2; ++h2)
#pragma unroll
    for (int f = 0; f < 8; ++f)
#pragma unroll
      for (int jj = 0; jj < 4; ++jj)
        st0(w16 + lg * 4 + jj, h2 * 128 + f * 16 + l15,
            (f16)(acc[h2][f][jj] * inv[jj]));

  // ---------- phase R ----------
#pragma unroll
  for (int a = 0; a < 2; ++a)
#pragma unroll
    for (int b = 0; b < 8; ++b) acc[a][b] = (f32x4)(0.f);
  stageB8(xT, 0);
#pragma unroll
  for (int s = 0; s < 16; ++s) {
    const int jt = s >> 1, ch = s & 1;
    VMW(0);
    barrier_fenced();
    if (s < 15) {
      const int ns = s + 1;
      stageB8(xT + (ns & 1) * 32768 + (ns >> 1) * 32, ns);
    }
    f16x8 af = ld0(arow, jt);
    __builtin_amdgcn_s_setprio(1);
#pragma unroll
    for (int f = 0; f < 8; ++f) {
      f16x8 bf = ldB8(s, f * 16 + l15);
      acc[ch][f] = __builtin_amdgcn_mfma_f32_16x16x32_f16(af, bf, acc[ch][f], 0, 0, 0);
    }
    __builtin_amdgcn_s_setprio(0);
  }
  barrier_fenced();
#pragma unroll
  for (int ch = 0; ch < 2; ++ch)
#pragma unroll
    for (int f = 0; f < 8; ++f)
#pragma unroll
      for (int jj = 0; jj < 4; ++jj)
        st0(w16 + lg * 4 + jj, ch * 128 + f * 16 + l15, (f16)acc[ch][f][jj]);

  // ---------- phase Z ----------
#pragma unroll
  for (int a = 0; a < 2; ++a)
#pragma unroll
    for (int b = 0; b < 8; ++b) acc[a][b] = (f32x4)(0.f);
  stageB8(GTh, 0);
#pragma unroll
  for (int s = 0; s < 16; ++s) {
    const int ct = s >> 1, dh = s & 1;
    VMW(0);
    barrier_fenced();
    if (s < 15) {
      const int ns = s + 1;
      stageB8(GTh + (ns & 1) * 32768 + (ns >> 1) * 32, ns);
    }
    f16x8 af = ld0(arow, ct);
    __builtin_amdgcn_s_setprio(1);
#pragma unroll
    for (int f = 0; f < 8; ++f) {
      f16x8 bf = ldB8(s, f * 16 + l15);
      acc[dh][f] = __builtin_amdgcn_mfma_f32_16x16x32_f16(af, bf, acc[dh][f], 0, 0, 0);
    }
    __builtin_amdgcn_s_setprio(0);
  }

  const long zb = (long)bc * 524288 + (long)(qt * 128) * 2048 + h * 256;
#pragma unroll
  for (int dh = 0; dh < 2; ++dh)
#pragma unroll
    for (int f = 0; f < 8; ++f)
#pragma unroll
      for (int jj = 0; jj < 4; ++jj) {
        int trow = w16 + lg * 4 + jj;
        int dm = dh * 128 + f * 16 + l15;
        Zp[zb + (long)trow * 2048 + dm] = (f16)acc[dh][f][jj];
      }
}

// ---------------- reduce2b: out = sum_h Zp + bo + sum_p bo2p ----------------
__global__ __launch_bounds__(256) void reduce2b(const f16* __restrict__ Zp,
                                                const float* __restrict__ bo2p,
                                                const float* __restrict__ bo,
                                                float* __restrict__ out) {
  int g = blockIdx.x * 256 + threadIdx.x;  // 4096 blocks
  int flat = g * 4;                        // 4,194,304 f32 output
  int dm = flat & 255;
  int t = (flat >> 8) & 255;
  int bc = flat >> 16;  // 0..63
  const f16* zp = Zp + (long)bc * 524288 + (long)t * 2048 + dm;
  float4 s = *(const float4*)(bo + dm);
#pragma unroll
  for (int p = 0; p < 4; ++p) {
    float4 bp = *(const float4*)(bo2p + p * 256 + dm);
    s.x += bp.x;
    s.y += bp.y;
    s.z += bp.z;
    s.w += bp.w;
  }
#pragma unroll
  for (int h = 0; h < 8; ++h) {
    f16x4 zv = *(const f16x4*)(zp + h * 256);
    s.x += (float)zv[0];
    s.y += (float)zv[1];
    s.z += (float)zv[2];
    s.w += (float)zv[3];
  }
  *(float4*)(out + flat) = s;
}

// ---------------- launch ----------------
// ws layout (bytes):
//   xb    @ 0         8388608    f16 [16384 tok][256 c]
//   xbT   @ 8388608   8388608    f16 [bc][256 c][256 t]
//   WqT2  @ 16777216  1048576    f16 [h*256+c][256 d]
//   WkT2  @ 17825792  1048576
//   WvT2  @ 18874368  1048576
//   WoT   @ 19922944  1048576    f16 [dm][h*256+d]
//   MT    @ 20987904  1048576    f16 [h][c'][c]
//   GT    @ 22036480  1048576    f16 [h][dm][c]
//   wv    @ 23085056  8192       f32 [h][c]
//   v     @ 23094272  524288     f32 [bc][h][j]
//   Zp    @ 23618560  67108864   f16 [bc][t][h*256+dm]
//   bo2p  @ 90727424  4096       f32 [4][dm]
extern "C" void kernel_launch(void* const* d_in, const int* in_sizes, int n_in,
                              void* d_out, int out_size, void* d_ws,
                              size_t ws_size, hipStream_t stream) {
  const float* x = (const float*)d_in[0];
  const float* Wq = (const float*)d_in[1];
  const float* bq = (const float*)d_in[2];
  const float* Wk = (const float*)d_in[3];
  const float* Wv = (const float*)d_in[5];
  const float* bv = (const float*)d_in[6];
  const float* Wo = (const float*)d_in[7];
  const float* bo = (const float*)d_in[8];

  char* ws = (char*)d_ws;
  f16* xb = (f16*)(ws + 0);
  f16* xbT = (f16*)(ws + 8388608);
  f16* WqT2 = (f16*)(ws + 16777216);
  f16* WkT2 = (f16*)(ws + 17825792);
  f16* WvT2 = (f16*)(ws + 18874368);
  f16* WoT = (f16*)(ws + 19922944);
  f16* MTws = (f16*)(ws + 20987904);
  f16* GTws = (f16*)(ws + 22036480);
  float* wvv = (float*)(ws + 23085056);
  float* vws = (float*)(ws + 23094272);
  f16* Zp = (f16*)(ws + 23618560);
  float* bo2p = (float*)(ws + 90727424);
  if (ws_size < 90727424ull + 4096ull) return;  // ~91MB

  prep_all3<<<2564, 256, 0, stream>>>(x, Wq, Wk, Wv, Wo, bv, xb, xbT, WqT2,
                                      WkT2, WvT2, WoT, bo2p);
  gemm_pre2<<<40, 256, 0, stream>>>(WqT2, WkT2, WvT2, WoT, bq, MTws, GTws, wvv);
  vcomp<<<64, 256, 0, stream>>>(xb, wvv, vws);
  // grid (bc, qt, h): same-bc blocks adjacent -> share XCD L2 for xB/xT
  attn_fused6<<<dim3(64, 2, 8), 512, 0, stream>>>(xb, xbT, MTws, GTws, vws, Zp);
  reduce2b<<<4096, 256, 0, stream>>>(Zp, bo2p, bo, (float*)d_out);
}

// Round 21
// 164.926 us; speedup vs baseline: 1.6504x; 1.6504x over previous
//
#include <hip/hip_runtime.h>
#include <hip/hip_fp16.h>

typedef _Float16 f16;
typedef _Float16 f16x8 __attribute__((ext_vector_type(8)));
typedef _Float16 f16x4 __attribute__((ext_vector_type(4)));
typedef float f32x4 __attribute__((ext_vector_type(4)));

#define GLB(p) ((const __attribute__((address_space(1))) void*)(p))
#define LDSP(p) ((__attribute__((address_space(3))) void*)(p))

__device__ __forceinline__ void gload16(const void* g, void* l) {
  __builtin_amdgcn_global_load_lds(GLB(g), LDSP(l), 16, 0, 0);
}

#define VMW(n) asm volatile("s_waitcnt vmcnt(" #n ")" ::: "memory")
__device__ __forceinline__ void barrier_fenced() {
  asm volatile("" ::: "memory");
  __builtin_amdgcn_s_barrier();
  asm volatile("" ::: "memory");
}

// ---------------- prep_all4: xpose + weight permute + bo2 partials (parallel) ------
// blocks 0..511    : xpose  (x -> xb [t][c] f16, xbT [bc][c][t] f16)
// blocks 512..2559 : weights (WqT2/WkT2/WvT2[h*256+c][d] = W[c][d*8+h];
//                             WoT[dm][h*256+d] = Wo[(d*8+h)][dm])
// blocks 2560..2591: bo2p[p][dm] = sum_{r in [p*64,p*64+64)} Wo[r][dm]*bv[r]
//                    (64 iters, 8 independent accumulators -> 8 loads in flight)
__global__ __launch_bounds__(256) void prep_all4(
    const float* __restrict__ x, const float* __restrict__ Wq,
    const float* __restrict__ Wk, const float* __restrict__ Wv,
    const float* __restrict__ Wo, const float* __restrict__ bv,
    f16* __restrict__ xb, f16* __restrict__ xbT, f16* __restrict__ WqT2,
    f16* __restrict__ WkT2, f16* __restrict__ WvT2, f16* __restrict__ WoT,
    float* __restrict__ bo2p) {
  __shared__ f16 t[32 * 268];
  const int bid = blockIdx.x;
  const int tid = threadIdx.x;
  if (bid < 512) {
    // ---- xpose ----
    const int bc = bid >> 3, tt = bid & 7;
    const long tbase = (long)(bc * 256 + tt * 32);
#pragma unroll
    for (int i = 0; i < 8; ++i) {
      int tr = (tid >> 6) + i * 4;  // 0..31
      int c4 = (tid & 63) * 4;
      float4 v = *(const float4*)(x + (tbase + tr) * 256 + c4);
      f16x4 o = {(f16)v.x, (f16)v.y, (f16)v.z, (f16)v.w};
      *(f16x4*)(xb + (tbase + tr) * 256 + c4) = o;
      *(f16x4*)(&t[tr * 268 + c4]) = o;
    }
    __syncthreads();
#pragma unroll
    for (int i = 0; i < 8; ++i) {
      int c = (tid >> 3) + i * 32;  // 0..255
      int t0 = (tid & 7) * 4;       // 0..28
      f16x4 v;
#pragma unroll
      for (int j = 0; j < 4; ++j) v[j] = t[(t0 + j) * 268 + c];
      *(f16x4*)(&xbT[(long)bc * 65536 + (long)c * 256 + tt * 32 + t0]) = v;
    }
  } else if (bid < 2560) {
    // ---- weight permute ----
    int g = (bid - 512) * 256 + tid;  // 0..524287
    int hc = g >> 8, d = g & 255;
    int h = hc >> 8, c = hc & 255;
    int src = c * 2048 + d * 8 + h;
    WqT2[g] = (f16)Wq[src];
    WkT2[g] = (f16)Wk[src];
    WvT2[g] = (f16)Wv[src];
    int dm = g >> 11, np = g & 2047;
    WoT[g] = (f16)Wo[((np & 255) * 8 + (np >> 8)) * 256 + dm];
  } else {
    // ---- bo2 partial p: 64 rows, 8 independent accumulators ----
    const int p = bid - 2560;  // 0..31
    const int dm = tid;
    const int r0 = p * 64;
    float a[8] = {};
#pragma unroll
    for (int b = 0; b < 8; ++b)
#pragma unroll
      for (int u = 0; u < 8; ++u)
        a[u] += Wo[(long)(r0 + b * 8 + u) * 256 + dm] * bv[r0 + b * 8 + u];
    float acc = 0.f;
#pragma unroll
    for (int u = 0; u < 8; ++u) acc += a[u];
    bo2p[p * 256 + dm] = acc;
  }
}

// ---------------- gemm_pre3: MT_h, GT_h (0..31) + wv (32..39) + bo2 (40) ------
__global__ __launch_bounds__(256) void gemm_pre3(
    const f16* __restrict__ WqT2, const f16* __restrict__ WkT2,
    const f16* __restrict__ WvT2, const f16* __restrict__ WoT,
    const float* __restrict__ bq, const float* __restrict__ bo,
    const float* __restrict__ bo2p, f16* __restrict__ MT, f16* __restrict__ GT,
    float* __restrict__ wv, float* __restrict__ bo2) {
  const int bid = blockIdx.x;
  const int tid = threadIdx.x;
  if (bid >= 40) {
    // ---- bo2 = bo + sum_32 bo2p (coalesced, L2-hot) ----
    float acc = bo[tid];
#pragma unroll
    for (int p = 0; p < 32; ++p) acc += bo2p[p * 256 + tid];
    bo2[tid] = acc;
    return;
  }
  if (bid >= 32) {
    // ---- wv for head h ----
    __shared__ float bql[256];
    const int h = bid - 32;
    bql[tid] = bq[tid * 8 + h];  // bql[d] = bq[d*8+h]
    __syncthreads();
    const f16* row = WkT2 + ((h * 256 + tid) << 8);
    float acc = 0.f;
#pragma unroll
    for (int d8 = 0; d8 < 32; ++d8) {
      f16x8 kv = *(const f16x8*)(row + d8 * 8);
#pragma unroll
      for (int e = 0; e < 8; ++e) acc += (float)kv[e] * bql[d8 * 8 + e];
    }
    wv[h * 256 + tid] = acc;
    return;
  }
  __shared__ __align__(16) char smem[49152];  // A 2x8KB @0, B 2x16KB @16384
  const int mat = bid >> 4, h = (bid >> 1) & 7, mt = bid & 1;
  const f16* A;
  long As;
  const f16* B;
  f16* C;
  if (mat == 0) {
    A = WkT2 + h * 65536 + mt * 32768;
    As = 256;
    B = WqT2 + h * 65536;
    C = MT + h * 65536 + mt * 32768;
  } else {
    A = WoT + h * 256 + (long)mt * 128 * 2048;
    As = 2048;
    B = WvT2 + h * 65536;
    C = GT + h * 65536 + mt * 32768;
  }
  const int lane = tid & 63, wid = tid >> 6;  // 4 waves
  const int l15 = lane & 15, lg = lane >> 4;
  const int w32 = wid * 32;

  auto stageA = [&](int ct) {
#pragma unroll
    for (int r = 0; r < 2; ++r) {
      int flat = r * 4096 + tid * 16;
      int row = flat >> 6;
      int kk = ct * 32 + (((flat ^ (((row >> 1) & 3) << 4)) & 63) >> 1);
      gload16(A + (long)row * As + kk, smem + (ct & 1) * 8192 + flat);
    }
  };
  auto stageB = [&](int ct) {
#pragma unroll
    for (int r = 0; r < 4; ++r) {
      int flat = r * 4096 + tid * 16;
      int row = flat >> 6;
      int kk = ct * 32 + (((flat ^ (((row >> 1) & 3) << 4)) & 63) >> 1);
      gload16(B + (long)row * 256 + kk, smem + 16384 + (ct & 1) * 16384 + flat);
    }
  };
  auto ldA = [&](int ct, int row) -> f16x8 {
    return *(const f16x8*)(smem + (ct & 1) * 8192 + row * 64 +
                           ((lg * 16) ^ (((row >> 1) & 3) << 4)));
  };
  auto ldB = [&](int ct, int row) -> f16x8 {
    return *(const f16x8*)(smem + 16384 + (ct & 1) * 16384 + row * 64 +
                           ((lg * 16) ^ (((row >> 1) & 3) << 4)));
  };

  f32x4 acc[2][16] = {};
  stageA(0);
  stageB(0);
  for (int ct = 0; ct < 8; ++ct) {
    VMW(0);
    barrier_fenced();
    if (ct < 7) {
      stageA(ct + 1);
      stageB(ct + 1);
    }
    f16x8 af[2];
#pragma unroll
    for (int i = 0; i < 2; ++i) af[i] = ldA(ct, w32 + i * 16 + l15);
#pragma unroll
    for (int f = 0; f < 16; ++f) {
      f16x8 bf = ldB(ct, f * 16 + l15);
#pragma unroll
      for (int i = 0; i < 2; ++i)
        acc[i][f] = __builtin_amdgcn_mfma_f32_16x16x32_f16(af[i], bf, acc[i][f], 0, 0, 0);
    }
  }
#pragma unroll
  for (int i = 0; i < 2; ++i)
#pragma unroll
    for (int f = 0; f < 16; ++f)
#pragma unroll
      for (int jj = 0; jj < 4; ++jj)
        C[(w32 + i * 16 + lg * 4 + jj) * 256 + f * 16 + l15] = (f16)acc[i][f][jj];
}

// ---------------- vcomp: v[bc][h][j] = sum_c xb[bc][j][c] * wv[h][c] ----------------
__global__ __launch_bounds__(256) void vcomp(const f16* __restrict__ xb,
                                             const float* __restrict__ wv,
                                             float* __restrict__ v) {
  __shared__ float wl[2048];
  const int bc = blockIdx.x, tid = threadIdx.x;
  for (int r = 0; r < 8; ++r) wl[r * 256 + tid] = wv[r * 256 + tid];
  __syncthreads();
  const f16* row = xb + (long)bc * 65536 + (long)tid * 256;
  float a[8] = {};
  for (int c8 = 0; c8 < 32; ++c8) {
    f16x8 xv = *(const f16x8*)(row + c8 * 8);
#pragma unroll
    for (int h = 0; h < 8; ++h) {
      float s = 0.f;
#pragma unroll
      for (int e = 0; e < 8; ++e) s += (float)xv[e] * wl[h * 256 + c8 * 8 + e];
      a[h] += s;
    }
  }
  for (int h = 0; h < 8; ++h) v[bc * 2048 + h * 256 + tid] = a[h];
}

// ---------------- attn_fused6 (verified: 125us, VGPR 100, no spill) ----
__global__ __launch_bounds__(512, 2) void attn_fused6(
    const f16* __restrict__ xb, const f16* __restrict__ xbT,
    const f16* __restrict__ MT, const f16* __restrict__ GT,
    const float* __restrict__ vw, f16* __restrict__ Zp) {
  __shared__ __align__(16) char smem[81920];
  const int tid = threadIdx.x;
  const int lane = tid & 63, wid = tid >> 6;  // 8 waves x 16 rows
  const int l15 = lane & 15, lg = lane >> 4;
  const int w16 = wid * 16;
  const int bc = blockIdx.x, qt = blockIdx.y, h = blockIdx.z;
  const f16* xB = xb + (long)bc * 65536;   // [t][c]
  const f16* xA = xB + qt * 32768;         // this block's 128 q rows
  const f16* xT = xbT + (long)bc * 65536;  // [c][t]
  const f16* MTh = MT + h * 65536;         // [c'][c]
  const f16* GTh = GT + h * 65536;         // [dm][c]

  float vv[2][8];
  {
    const float* vb = vw + bc * 2048 + h * 256;
#pragma unroll
    for (int h2 = 0; h2 < 2; ++h2)
#pragma unroll
      for (int f = 0; f < 8; ++f) vv[h2][f] = vb[h2 * 128 + f * 16 + l15];
  }

  auto stageB8 = [&](const f16* src, int s) {  // [128 rows][32 k] 8KB, 1 pass
    int flat = tid * 16;
    int row = flat >> 6;
    int kk = ((flat ^ (((row >> 1) & 3) << 4)) & 63) >> 1;
    gload16(src + (long)row * 256 + kk, smem + 65536 + (s & 1) * 8192 + flat);
  };
  auto ldB8 = [&](int s, int row) -> f16x8 {
    return *(const f16x8*)(smem + 65536 + (s & 1) * 8192 + row * 64 +
                           ((lg * 16) ^ (((row >> 1) & 3) << 4)));
  };
  auto stageA8 = [&](int ct) {  // xA tile [128][32] into region0 bufs
    int flat = tid * 16;
    int row = flat >> 6;
    int kk = ct * 32 + (((flat ^ (((row >> 1) & 3) << 4)) & 63) >> 1);
    gload16(xA + (long)row * 256 + kk, smem + (ct & 1) * 8192 + flat);
  };
  auto ldA8 = [&](int ct, int row) -> f16x8 {
    return *(const f16x8*)(smem + (ct & 1) * 8192 + row * 64 +
                           ((lg * 16) ^ (((row >> 1) & 3) << 4)));
  };
  auto st0 = [&](int row, int col, f16 val) {
    *(f16*)(smem + row * 512 + ((col * 2) ^ ((row & 7) << 4))) = val;
  };
  auto ld0 = [&](int row, int kt) -> f16x8 {
    return *(const f16x8*)(smem + row * 512 +
                           ((kt * 64 + lg * 16) ^ ((row & 7) << 4)));
  };

  const int arow = w16 + l15;
  f32x4 acc[2][8];

  // ---------- phase T ----------
#pragma unroll
  for (int a = 0; a < 2; ++a)
#pragma unroll
    for (int b = 0; b < 8; ++b) acc[a][b] = (f32x4)(0.f);
  stageA8(0);
  stageB8(MTh, 0);
#pragma unroll
  for (int s = 0; s < 16; ++s) {
    const int ct = s >> 1, h2 = s & 1;
    VMW(0);
    barrier_fenced();
    if (s < 15) {
      const int ns = s + 1;
      stageB8(MTh + (ns & 1) * 32768 + (ns >> 1) * 32, ns);
      if ((ns & 1) == 0) stageA8(ns >> 1);
    }
    f16x8 af = ldA8(ct, arow);
    __builtin_amdgcn_s_setprio(1);
#pragma unroll
    for (int f = 0; f < 8; ++f) {
      f16x8 bf = ldB8(s, f * 16 + l15);
      acc[h2][f] = __builtin_amdgcn_mfma_f32_16x16x32_f16(af, bf, acc[h2][f], 0, 0, 0);
    }
    __builtin_amdgcn_s_setprio(0);
  }
  barrier_fenced();
#pragma unroll
  for (int h2 = 0; h2 < 2; ++h2)
#pragma unroll
    for (int f = 0; f < 8; ++f)
#pragma unroll
      for (int jj = 0; jj < 4; ++jj)
        st0(w16 + lg * 4 + jj, h2 * 128 + f * 16 + l15, (f16)acc[h2][f][jj]);

  // ---------- phase S ----------
#pragma unroll
  for (int a = 0; a < 2; ++a)
#pragma unroll
    for (int b = 0; b < 8; ++b) acc[a][b] = (f32x4)(0.f);
  stageB8(xB, 0);
#pragma unroll
  for (int s = 0; s < 16; ++s) {
    const int ct = s >> 1, jh = s & 1;
    VMW(0);
    barrier_fenced();
    if (s < 15) {
      const int ns = s + 1;
      stageB8(xB + (ns & 1) * 32768 + (ns >> 1) * 32, ns);
    }
    f16x8 af = ld0(arow, ct);
    __builtin_amdgcn_s_setprio(1);
#pragma unroll
    for (int f = 0; f < 8; ++f) {
      f16x8 bf = ldB8(s, f * 16 + l15);
      acc[jh][f] = __builtin_amdgcn_mfma_f32_16x16x32_f16(af, bf, acc[jh][f], 0, 0, 0);
    }
    __builtin_amdgcn_s_setprio(0);
  }
  barrier_fenced();

  // ---------- softmax over 256 j (rows wave-private) ----------
  const float SCL = 0.0625f * 1.44269504089f;
  float inv[4];
#pragma unroll
  for (int jj = 0; jj < 4; ++jj) {
    float m_ = acc[0][0][jj] + vv[0][0];
#pragma unroll
    for (int h2 = 0; h2 < 2; ++h2)
#pragma unroll
      for (int f = 0; f < 8; ++f)
        m_ = fmaxf(m_, acc[h2][f][jj] + vv[h2][f]);
#pragma unroll
    for (int off = 1; off < 16; off <<= 1) m_ = fmaxf(m_, __shfl_xor(m_, off, 64));
    float s_ = 0.f;
#pragma unroll
    for (int h2 = 0; h2 < 2; ++h2)
#pragma unroll
      for (int f = 0; f < 8; ++f) {
        float e = __builtin_exp2f((acc[h2][f][jj] + vv[h2][f] - m_) * SCL);
        acc[h2][f][jj] = e;
        s_ += e;
      }
#pragma unroll
    for (int off = 1; off < 16; off <<= 1) s_ += __shfl_xor(s_, off, 64);
    inv[jj] = 1.f / s_;
  }
#pragma unroll
  for (int h2 = 0; h2 < 2; ++h2)
#pragma unroll
    for (int f = 0; f < 8; ++f)
#pragma unroll
      for (int jj = 0; jj < 4; ++jj)
        st0(w16 + lg * 4 + jj, h2 * 128 + f * 16 + l15,
            (f16)(acc[h2][f][jj] * inv[jj]));

  // ---------- phase R ----------
#pragma unroll
  for (int a = 0; a < 2; ++a)
#pragma unroll
    for (int b = 0; b < 8; ++b) acc[a][b] = (f32x4)(0.f);
  stageB8(xT, 0);
#pragma unroll
  for (int s = 0; s < 16; ++s) {
    const int jt = s >> 1, ch = s & 1;
    VMW(0);
    barrier_fenced();
    if (s < 15) {
      const int ns = s + 1;
      stageB8(xT + (ns & 1) * 32768 + (ns >> 1) * 32, ns);
    }
    f16x8 af = ld0(arow, jt);
    __builtin_amdgcn_s_setprio(1);
#pragma unroll
    for (int f = 0; f < 8; ++f) {
      f16x8 bf = ldB8(s, f * 16 + l15);
      acc[ch][f] = __builtin_amdgcn_mfma_f32_16x16x32_f16(af, bf, acc[ch][f], 0, 0, 0);
    }
    __builtin_amdgcn_s_setprio(0);
  }
  barrier_fenced();
#pragma unroll
  for (int ch = 0; ch < 2; ++ch)
#pragma unroll
    for (int f = 0; f < 8; ++f)
#pragma unroll
      for (int jj = 0; jj < 4; ++jj)
        st0(w16 + lg * 4 + jj, ch * 128 + f * 16 + l15, (f16)acc[ch][f][jj]);

  // ---------- phase Z ----------
#pragma unroll
  for (int a = 0; a < 2; ++a)
#pragma unroll
    for (int b = 0; b < 8; ++b) acc[a][b] = (f32x4)(0.f);
  stageB8(GTh, 0);
#pragma unroll
  for (int s = 0; s < 16; ++s) {
    const int ct = s >> 1, dh = s & 1;
    VMW(0);
    barrier_fenced();
    if (s < 15) {
      const int ns = s + 1;
      stageB8(GTh + (ns & 1) * 32768 + (ns >> 1) * 32, ns);
    }
    f16x8 af = ld0(arow, ct);
    __builtin_amdgcn_s_setprio(1);
#pragma unroll
    for (int f = 0; f < 8; ++f) {
      f16x8 bf = ldB8(s, f * 16 + l15);
      acc[dh][f] = __builtin_amdgcn_mfma_f32_16x16x32_f16(af, bf, acc[dh][f], 0, 0, 0);
    }
    __builtin_amdgcn_s_setprio(0);
  }

  const long zb = (long)bc * 524288 + (long)(qt * 128) * 2048 + h * 256;
#pragma unroll
  for (int dh = 0; dh < 2; ++dh)
#pragma unroll
    for (int f = 0; f < 8; ++f)
#pragma unroll
      for (int jj = 0; jj < 4; ++jj) {
        int trow = w16 + lg * 4 + jj;
        int dm = dh * 128 + f * 16 + l15;
        Zp[zb + (long)trow * 2048 + dm] = (f16)acc[dh][f][jj];
      }
}

// ---------------- reduce2: out = sum_h Zp + bo2 ----------------
__global__ __launch_bounds__(256) void reduce2(const f16* __restrict__ Zp,
                                               const float* __restrict__ bo2,
                                               float* __restrict__ out) {
  int g = blockIdx.x * 256 + threadIdx.x;  // 4096 blocks
  int flat = g * 4;                        // 4,194,304 f32 output
  int dm = flat & 255;
  int t = (flat >> 8) & 255;
  int bc = flat >> 16;  // 0..63
  const f16* zp = Zp + (long)bc * 524288 + (long)t * 2048 + dm;
  float4 s = *(const float4*)(bo2 + dm);
#pragma unroll
  for (int h = 0; h < 8; ++h) {
    f16x4 zv = *(const f16x4*)(zp + h * 256);
    s.x += (float)zv[0];
    s.y += (float)zv[1];
    s.z += (float)zv[2];
    s.w += (float)zv[3];
  }
  *(float4*)(out + flat) = s;
}

// ---------------- launch ----------------
// ws layout (bytes):
//   xb    @ 0         8388608    f16 [16384 tok][256 c]
//   xbT   @ 8388608   8388608    f16 [bc][256 c][256 t]
//   WqT2  @ 16777216  1048576    f16 [h*256+c][256 d]
//   WkT2  @ 17825792  1048576
//   WvT2  @ 18874368  1048576
//   WoT   @ 19922944  1048576    f16 [dm][h*256+d]
//   MT    @ 20987904  1048576    f16 [h][c'][c]
//   GT    @ 22036480  1048576    f16 [h][dm][c]
//   wv    @ 23085056  8192       f32 [h][c]
//   v     @ 23094272  524288     f32 [bc][h][j]
//   Zp    @ 23618560  67108864   f16 [bc][t][h*256+dm]
//   bo2p  @ 90727424  32768      f32 [32][dm]
//   bo2   @ 90760192  1024       f32 [dm]
extern "C" void kernel_launch(void* const* d_in, const int* in_sizes, int n_in,
                              void* d_out, int out_size, void* d_ws,
                              size_t ws_size, hipStream_t stream) {
  const float* x = (const float*)d_in[0];
  const float* Wq = (const float*)d_in[1];
  const float* bq = (const float*)d_in[2];
  const float* Wk = (const float*)d_in[3];
  const float* Wv = (const float*)d_in[5];
  const float* bv = (const float*)d_in[6];
  const float* Wo = (const float*)d_in[7];
  const float* bo = (const float*)d_in[8];

  char* ws = (char*)d_ws;
  f16* xb = (f16*)(ws + 0);
  f16* xbT = (f16*)(ws + 8388608);
  f16* WqT2 = (f16*)(ws + 16777216);
  f16* WkT2 = (f16*)(ws + 17825792);
  f16* WvT2 = (f16*)(ws + 18874368);
  f16* WoT = (f16*)(ws + 19922944);
  f16* MTws = (f16*)(ws + 20987904);
  f16* GTws = (f16*)(ws + 22036480);
  float* wvv = (float*)(ws + 23085056);
  float* vws = (float*)(ws + 23094272);
  f16* Zp = (f16*)(ws + 23618560);
  float* bo2p = (float*)(ws + 90727424);
  float* bo2 = (float*)(ws + 90760192);
  if (ws_size < 90760192ull + 1024ull) return;  // ~91MB

  prep_all4<<<2592, 256, 0, stream>>>(x, Wq, Wk, Wv, Wo, bv, xb, xbT, WqT2,
                                      WkT2, WvT2, WoT, bo2p);
  gemm_pre3<<<41, 256, 0, stream>>>(WqT2, WkT2, WvT2, WoT, bq, bo, bo2p, MTws,
                                    GTws, wvv, bo2);
  vcomp<<<64, 256, 0, stream>>>(xb, wvv, vws);
  // grid (bc, qt, h): same-bc blocks adjacent -> share XCD L2 for xB/xT
  attn_fused6<<<dim3(64, 2, 8), 512, 0, stream>>>(xb, xbT, MTws, GTws, vws, Zp);
  reduce2<<<4096, 256, 0, stream>>>(Zp, bo2, (float*)d_out);
}